// Round 11
// baseline (124.835 us; speedup 1.0000x reference)
//
#include <hip/hip_runtime.h>

#define Bn 2
#define Cn 3
#define Hn 160
#define Wn 160
#define SPANc 11
#define Kc 23
#define HWn (Hn * Wn)
#define PW 182                 // padded dim: 160 + 2*11
#define PP (PW * PW)
#define LAMc 0.15f
#define TJ 32                  // j-tile width (= lanes 0..31)
#define Gc 4                   // centers per thread (vertical)
#define TI 32                  // i-tile height = 8 ty-groups * Gc
#define NROWMAX (TI + 12 - 1)  // 43 staged rows (di-half 0: nd=12)
#define NRECMAX (NROWMAX * TJ) // 1376 records in LDS (33.0 KB -> 4 blocks/CU)
#define CEXP (-0.72134752f)    // -0.5 * log2(e)
#define NPREP ((Bn * PP + 255) / 256)   // 259 prep blocks
#define NBLK (5 * 10 * 46)              // 2300 gcrf blocks

__device__ __forceinline__ float wave_reduce64(float v) {
#pragma unroll
    for (int off = 32; off > 0; off >>= 1) v += __shfl_down(v, off, 64);
    return v;
}

// Fused: zero halo + softmax/pack interior + CE block-partials + zero acc/counter.
// Records: gA=[img0,img1,img2,ys0], gB=[ys1,ys2] (ys = src*y); halo = 0.
__global__ __launch_bounds__(256) void prep_kernel(
    const float* __restrict__ logit, const int* __restrict__ target,
    const float* __restrict__ image, const float* __restrict__ srcmap,
    const float* __restrict__ dstmap, float4* __restrict__ gA,
    float2* __restrict__ gB, float4* __restrict__ cvec,
    float* __restrict__ pc, double* __restrict__ acc,
    unsigned int* __restrict__ counter)
{
    int idx = blockIdx.x * 256 + threadIdx.x;
    float ce = 0.0f;
    if (idx < Bn * PP) {
        int b   = idx / PP;
        int rem = idx - b * PP;
        int ip  = rem / PW;
        int jp  = rem - ip * PW;
        int i = ip - SPANc, j = jp - SPANc;
        if ((unsigned)i < (unsigned)Hn && (unsigned)j < (unsigned)Wn) {
            int r = i * Wn + j;
            int p = b * HWn + r;
            const float* lg = logit + (size_t)b * Cn * HWn + r;
            float l0 = lg[0], l1 = lg[HWn], l2 = lg[2 * HWn];
            float m = fmaxf(l0, fmaxf(l1, l2));
            float e0 = __expf(l0 - m), e1 = __expf(l1 - m), e2 = __expf(l2 - m);
            float s = e0 + e1 + e2;
            float inv = 1.0f / s;
            float y0 = e0 * inv, y1 = e1 * inv, y2 = e2 * inv;
            float lse = m + __logf(s);

            const float* im = image + (size_t)b * 3 * HWn + r;
            float i0v = im[0], i1v = im[HWn], i2v = im[2 * HWn];
            float sv = srcmap[p];
            float dv = dstmap[p];

            gA[idx] = make_float4(i0v, i1v, i2v, sv * y0);
            gB[idx] = make_float2(sv * y1, sv * y2);

            float md = LAMc * (1.0f - dv);
            cvec[p] = make_float4(md * (1.0f - y0), md * (1.0f - y1),
                                  md * (1.0f - y2), 0.0f);

            int t = target[p];
            float lt = (t == 0) ? l0 : ((t == 1) ? l1 : l2);
            ce = (lse - lt) * dv;
        } else {
            gA[idx] = make_float4(0.f, 0.f, 0.f, 0.f);
            gB[idx] = make_float2(0.f, 0.f);
        }
    }
    if (idx == 0) { *acc = 0.0; *counter = 0u; }  // gcrf launches after this completes

    float v = wave_reduce64(ce);
    __shared__ float wsum[4];
    int tid = threadIdx.x;
    if ((tid & 63) == 0) wsum[tid >> 6] = v;
    __syncthreads();
    if (tid == 0) pc[blockIdx.x] = wsum[0] + wsum[1] + wsum[2] + wsum[3];
}

__device__ __forceinline__ void tap(const float4 pa, const float2 pb,
                                    float cA0, float cA1, float cA2,
                                    bool xy_on, float dy2, float dxv,
                                    float& e0, float& e1, float& e2)
{
    float d0 = fmaf(pa.x, -10.0f, cA0);
    float d1 = fmaf(pa.y, -10.0f, cA1);
    float d2 = fmaf(pa.z, -10.0f, cA2);
    float ss = fmaf(d0, d0, fmaf(d1, d1, d2 * d2));
    float k = exp2f(ss * CEXP);
    if (xy_on) k += exp2f(fmaf(dxv, dxv, dy2) * CEXP);   // exec-masked, ~0 lanes mostly
    e0 = fmaf(k, pa.w, e0);
    e1 = fmaf(k, pb.x, e1);
    e2 = fmaf(k, pb.y, e2);
}

// Window kernel. Grid: (5, 5*B, 46) = 2300 blocks. Block (32,8).
// blockIdx.z encodes (dj, di-half): each block covers one dj column and half
// the di range (nd = 12 or 11 taps). Staged rows = TI + nd - 1 (43/42),
// LDS 33.0 KB -> 4 blocks/CU (16 waves/CU). Last block reduces CE partials
// + gcrf acc and writes the scalar (finalize fused).
__global__ __launch_bounds__(256) void gcrf_kernel(
    const float4* __restrict__ gA, const float2* __restrict__ gB,
    const float4* __restrict__ cvec, const float* __restrict__ pc,
    double* __restrict__ acc, unsigned int* __restrict__ counter,
    float* __restrict__ out)
{
    __shared__ float4 sA[NRECMAX];   // img0,img1,img2,ys0
    __shared__ float2 sB[NRECMAX];   // ys1,ys2

    int tx = threadIdx.x;                 // 0..31 (j)
    int ty = threadIdx.y;                 // 0..7  (i-group)
    int tid = ty * TJ + tx;
    int jx = blockIdx.x;
    int j  = jx * TJ + tx;
    int by = blockIdx.y;
    int b  = by / 5;
    int it = by - b * 5;
    int i0g = it * TI + ty * Gc;          // first center row of this thread
    int bz = blockIdx.z;
    int dj   = bz >> 1;                   // 0..22
    int half = bz & 1;                    // 0 or 1
    int d0 = half * 12;                   // di range [d0, d0+nd)
    int nd = 12 - half;                   // 12 or 11

    // stage rows: padded rows [it*TI + d0, it*TI + d0 + TI + nd - 1)
    int nrec = (TI + nd - 1) * TJ;        // 1376 or 1344
    size_t g0 = (size_t)b * PP + (size_t)(it * TI + d0) * PW + (jx * TJ + dj);
    for (int n = tid; n < nrec; n += 256) {
        int rr = n >> 5, cc = n & 31;
        size_t gi = g0 + (size_t)rr * PW + cc;
        sA[n] = gA[gi];
        sB[n] = gB[gi];
    }
    __syncthreads();

    // center colors: center (i0g+c) at staged row (i0g+c) + SPANc - (i0g_block + d0)
    // = lty + c + (SPANc - d0); for half=1 that is lty + c - 1 >= 0 (lty+c >= 1 when
    // needed; c=0,lty=0 gives -1 but its img is only used for taps, fetch from cvec-side
    // instead: read center colors from gA directly (global, L2-hit) to stay safe.
    int lty = ty * Gc;
    float cA0[Gc], cA1[Gc], cA2[Gc];
    {
        size_t crow = (size_t)b * PP + (size_t)(i0g + SPANc) * PW + (j + SPANc);
#pragma unroll
        for (int c = 0; c < Gc; ++c) {
            float4 cr = gA[crow + (size_t)c * PW];
            cA0[c] = cr.x; cA1[c] = cr.y; cA2[c] = cr.z;
        }
    }

    // k_xy < 2.3e-29 unless both i<16 and j<16 (source-bug form: d = c - p/6)
    bool xy_on = (j < 16) && (i0g < 16);
    float dy = (float)j - (float)(j + dj - SPANc) * (1.0f / 6.0f);
    float dy2 = dy * dy;
    float fi0 = (float)i0g;

    float eg[Gc][3];
#pragma unroll
    for (int c = 0; c < Gc; ++c) { eg[c][0] = 0.f; eg[c][1] = 0.f; eg[c][2] = 0.f; }

    int lbase = lty * TJ + tx;
    // r = c + (di - d0); staged row lty + r; runtime bound keeps loop rolled (low VGPR)
    for (int r = 0; r < nd + Gc - 1; ++r) {
        float4 pa = sA[lbase + r * TJ];
        float2 pb = sB[lbase + r * TJ];
        float fpi = fi0 + (float)(r + d0 - SPANc);
#pragma unroll
        for (int c = 0; c < Gc; ++c) {
            if ((unsigned)(r - c) < (unsigned)nd) {   // wave-uniform branch
                tap(pa, pb, cA0[c], cA1[c], cA2[c], xy_on, dy2,
                    fi0 + (float)c - fpi * (1.0f / 6.0f),
                    eg[c][0], eg[c][1], eg[c][2]);
            }
        }
    }

    // epilogue: cvec already holds lam*(1-dst)*(1-y_c)
    const float4* cv = cvec + ((size_t)b * HWn + (size_t)i0g * Wn + j);
    float contrib = 0.0f;
#pragma unroll
    for (int c = 0; c < Gc; ++c) {
        float4 t = cv[(size_t)c * Wn];
        contrib += eg[c][0] * t.x + eg[c][1] * t.y + eg[c][2] * t.z;
    }

    float v = wave_reduce64(contrib);
    __shared__ float wsum[4];
    __shared__ int lastflag;
    if ((tid & 63) == 0) wsum[tid >> 6] = v;
    __syncthreads();
    if (tid == 0) {
        atomicAdd(acc, (double)(wsum[0] + wsum[1] + wsum[2] + wsum[3]));
        __threadfence();
        unsigned int old = atomicAdd(counter, 1u);
        lastflag = (old == NBLK - 1) ? 1 : 0;
    }
    __syncthreads();
    if (lastflag) {
        // fused finalize: sum CE partials + gcrf accumulator -> scalar loss
        float s = 0.0f;
        if (tid < NPREP) s += pc[tid];
        if (tid + 256 < NPREP) s += pc[tid + 256];
        float v2 = wave_reduce64(s);
        if ((tid & 63) == 0) wsum[tid >> 6] = v2;
        __syncthreads();
        if (tid == 0) {
            double tot = atomicAdd(acc, 0.0);   // device-scope coherent read
            tot += (double)(wsum[0] + wsum[1] + wsum[2] + wsum[3]);
            out[0] = (float)(tot * (1.0 / (double)(Bn * HWn)));
        }
    }
}

extern "C" void kernel_launch(void* const* d_in, const int* in_sizes, int n_in,
                              void* d_out, int out_size, void* d_ws, size_t ws_size,
                              hipStream_t stream)
{
    const float* logit  = (const float*)d_in[0];
    const int*   target = (const int*)d_in[1];
    const float* image  = (const float*)d_in[2];
    const float* srcmap = (const float*)d_in[3];
    const float* dstmap = (const float*)d_in[4];
    float* out = (float*)d_out;

    const size_t NRECG = (size_t)Bn * PP;   // 66,248 padded records
    double*       acc     = (double*)d_ws;
    unsigned int* counter = (unsigned int*)((char*)d_ws + 128);
    float*        pc      = (float*)((char*)d_ws + 256);         // 259 CE partials
    float4*       gA      = (float4*)((char*)d_ws + 4096);
    float2*       gB      = (float2*)((char*)d_ws + 4096 + NRECG * 16);
    float4*       cvec    = (float4*)((char*)d_ws + 4096 + NRECG * 24);

    prep_kernel<<<NPREP, 256, 0, stream>>>(logit, target, image, srcmap, dstmap,
                                           gA, gB, cvec, pc, acc, counter);
    dim3 grid(Wn / TJ, (Hn / TI) * Bn, 46);
    dim3 blk(TJ, 8);
    gcrf_kernel<<<grid, blk, 0, stream>>>(gA, gB, cvec, pc, acc, counter, out);
}

// Round 13
// 102.230 us; speedup vs baseline: 1.2211x; 1.2211x over previous
//
#include <hip/hip_runtime.h>

#define Bn 2
#define Cn 3
#define Hn 160
#define Wn 160
#define SPANc 11
#define Kc 23
#define HWn (Hn * Wn)
#define PW 182                 // padded dim: 160 + 2*11
#define PP (PW * PW)
#define LAMc 0.15f
#define TJ 32                  // j-tile width (= lanes 0..31)
#define Gc 4                   // centers per thread (vertical)
#define TI 32                  // i-tile height = 8 ty-groups * Gc
#define NROW (TI + Kc - 1)     // 54 staged rows
#define NREC (NROW * TJ)       // 1728 records in LDS (41.5 KB)
#define CEXP (-0.72134752f)    // -0.5 * log2(e)
#define SRGB_S (0.84932190f)   // sqrt(0.5*log2(e)); img pre-scaled so krgb = exp2(-ss)
#define NPREP ((Bn * PP + 255) / 256)   // 259 prep blocks
#define NBLK (5 * 10 * 23)              // 1150 gcrf blocks

__device__ __forceinline__ float wave_reduce64(float v) {
#pragma unroll
    for (int off = 32; off > 0; off >>= 1) v += __shfl_down(v, off, 64);
    return v;
}

// Fused: zero halo + softmax/pack interior + CE block-partials + zero acc/counter.
// Records: gA=[s*img0,s*img1,s*img2,ys0], gB=[ys1,ys2] (ys = src*y); halo = 0.
__global__ __launch_bounds__(256) void prep_kernel(
    const float* __restrict__ logit, const int* __restrict__ target,
    const float* __restrict__ image, const float* __restrict__ srcmap,
    const float* __restrict__ dstmap, float4* __restrict__ gA,
    float2* __restrict__ gB, float4* __restrict__ cvec,
    float* __restrict__ pc, double* __restrict__ acc,
    unsigned int* __restrict__ counter)
{
    int idx = blockIdx.x * 256 + threadIdx.x;
    float ce = 0.0f;
    if (idx < Bn * PP) {
        int b   = idx / PP;
        int rem = idx - b * PP;
        int ip  = rem / PW;
        int jp  = rem - ip * PW;
        int i = ip - SPANc, j = jp - SPANc;
        if ((unsigned)i < (unsigned)Hn && (unsigned)j < (unsigned)Wn) {
            int r = i * Wn + j;
            int p = b * HWn + r;
            const float* lg = logit + (size_t)b * Cn * HWn + r;
            float l0 = lg[0], l1 = lg[HWn], l2 = lg[2 * HWn];
            float m = fmaxf(l0, fmaxf(l1, l2));
            float e0 = __expf(l0 - m), e1 = __expf(l1 - m), e2 = __expf(l2 - m);
            float s = e0 + e1 + e2;
            float inv = 1.0f / s;
            float y0 = e0 * inv, y1 = e1 * inv, y2 = e2 * inv;
            float lse = m + __logf(s);

            const float* im = image + (size_t)b * 3 * HWn + r;
            float i0v = im[0] * SRGB_S, i1v = im[HWn] * SRGB_S, i2v = im[2 * HWn] * SRGB_S;
            float sv = srcmap[p];
            float dv = dstmap[p];

            gA[idx] = make_float4(i0v, i1v, i2v, sv * y0);
            gB[idx] = make_float2(sv * y1, sv * y2);

            float md = LAMc * (1.0f - dv);
            cvec[p] = make_float4(md * (1.0f - y0), md * (1.0f - y1),
                                  md * (1.0f - y2), 0.0f);

            int t = target[p];
            float lt = (t == 0) ? l0 : ((t == 1) ? l1 : l2);
            ce = (lse - lt) * dv;
        } else {
            gA[idx] = make_float4(0.f, 0.f, 0.f, 0.f);
            gB[idx] = make_float2(0.f, 0.f);
        }
    }
    if (idx == 0) { *acc = 0.0; *counter = 0u; }  // gcrf launches after this completes

    float v = wave_reduce64(ce);
    __shared__ float wsum[4];
    int tid = threadIdx.x;
    if ((tid & 63) == 0) wsum[tid >> 6] = v;
    __syncthreads();
    if (tid == 0) pc[blockIdx.x] = wsum[0] + wsum[1] + wsum[2] + wsum[3];
}

__device__ __forceinline__ void tap(const float4 pa, const float2 pb,
                                    float cA0, float cA1, float cA2,
                                    bool xy_on, float dy2, float dxv,
                                    float& e0, float& e1, float& e2)
{
    float d0 = fmaf(pa.x, -10.0f, cA0);   // both pre-scaled by SRGB_S
    float d1 = fmaf(pa.y, -10.0f, cA1);
    float d2 = fmaf(pa.z, -10.0f, cA2);
    float ss = fmaf(d0, d0, fmaf(d1, d1, d2 * d2));   // = 0.7213 * sum(d_true^2)
    float k = exp2f(-ss);                             // neg folds into v_exp modifier
    if (xy_on) k += exp2f(fmaf(dxv, dxv, dy2) * CEXP);   // exec-masked, rare
    e0 = fmaf(k, pa.w, e0);
    e1 = fmaf(k, pb.x, e1);
    e2 = fmaf(k, pb.y, e2);
}

// Window kernel. Grid: (5, 5*B, 23) = 1150 blocks. Block (32,8). One dj per block.
// Stage 54x32 records (41.5 KB LDS), 4 vertically-adjacent centers per thread over
// 23 di taps. Static 3-phase r-loop (R6/R10-proven shape). Last block reduces CE
// partials + gcrf acc and writes the scalar (finalize fused, R11-proven machinery).
__global__ __launch_bounds__(256) void gcrf_kernel(
    const float4* __restrict__ gA, const float2* __restrict__ gB,
    const float4* __restrict__ cvec, const float* __restrict__ pc,
    double* __restrict__ acc, unsigned int* __restrict__ counter,
    float* __restrict__ out)
{
    __shared__ float4 sA[NREC];   // s*img0,s*img1,s*img2,ys0
    __shared__ float2 sB[NREC];   // ys1,ys2

    int tx = threadIdx.x;                 // 0..31 (j)
    int ty = threadIdx.y;                 // 0..7  (i-group)
    int tid = ty * TJ + tx;
    int jx = blockIdx.x;
    int j  = jx * TJ + tx;
    int by = blockIdx.y;
    int b  = by / 5;
    int it = by - b * 5;
    int i0g = it * TI + ty * Gc;          // first center row of this thread
    int dj = blockIdx.z;                  // 0..22

    size_t g0 = (size_t)b * PP + (size_t)(it * TI) * PW + (jx * TJ + dj);
    for (int n = tid; n < NREC; n += 256) {
        int rr = n >> 5, cc = n & 31;
        size_t gi = g0 + (size_t)rr * PW + cc;
        sA[n] = gA[gi];
        sB[n] = gB[gi];
    }
    __syncthreads();

    int lbase = ty * Gc * TJ + tx;        // LDS index of (local row ty*Gc, col tx)
    float cA0[Gc], cA1[Gc], cA2[Gc];
#pragma unroll
    for (int c = 0; c < Gc; ++c) {
        float4 cr = sA[lbase + (c + SPANc) * TJ];
        cA0[c] = cr.x; cA1[c] = cr.y; cA2[c] = cr.z;
    }

    // k_xy < 2.3e-29 unless both i<16 and j<16 (source-bug form: d = c - p/6)
    bool xy_on = (j < 16) && (i0g < 16);
    float dy = (float)j - (float)(j + dj - SPANc) * (1.0f / 6.0f);
    float dy2 = dy * dy;
    float fi0 = (float)i0g;

    float eg[Gc][3];
#pragma unroll
    for (int c = 0; c < Gc; ++c) { eg[c][0] = 0.f; eg[c][1] = 0.f; eg[c][2] = 0.f; }

    // prologue r=0..2: center c active iff c <= r
#pragma unroll
    for (int r = 0; r < 3; ++r) {
        float4 pa = sA[lbase + r * TJ];
        float2 pb = sB[lbase + r * TJ];
        float fpi = fi0 + (float)(r - SPANc);
#pragma unroll
        for (int c = 0; c < 3; ++c) {
            if (c > r) continue;
            tap(pa, pb, cA0[c], cA1[c], cA2[c], xy_on, dy2,
                fi0 + (float)c - fpi * (1.0f / 6.0f), eg[c][0], eg[c][1], eg[c][2]);
        }
    }
    // main r=3..22: all 4 centers active
#pragma unroll 2
    for (int r = 3; r <= 22; ++r) {
        float4 pa = sA[lbase + r * TJ];
        float2 pb = sB[lbase + r * TJ];
        float fpi = fi0 + (float)(r - SPANc);
#pragma unroll
        for (int c = 0; c < Gc; ++c) {
            tap(pa, pb, cA0[c], cA1[c], cA2[c], xy_on, dy2,
                fi0 + (float)c - fpi * (1.0f / 6.0f), eg[c][0], eg[c][1], eg[c][2]);
        }
    }
    // epilogue r=23..25: center c active iff c >= r-22
#pragma unroll
    for (int r = 23; r <= 25; ++r) {
        float4 pa = sA[lbase + r * TJ];
        float2 pb = sB[lbase + r * TJ];
        float fpi = fi0 + (float)(r - SPANc);
#pragma unroll
        for (int c = 1; c < Gc; ++c) {
            if (c < r - 22) continue;
            tap(pa, pb, cA0[c], cA1[c], cA2[c], xy_on, dy2,
                fi0 + (float)c - fpi * (1.0f / 6.0f), eg[c][0], eg[c][1], eg[c][2]);
        }
    }

    // epilogue: cvec already holds lam*(1-dst)*(1-y_c)
    const float4* cv = cvec + ((size_t)b * HWn + (size_t)i0g * Wn + j);
    float contrib = 0.0f;
#pragma unroll
    for (int c = 0; c < Gc; ++c) {
        float4 t = cv[(size_t)c * Wn];
        contrib += eg[c][0] * t.x + eg[c][1] * t.y + eg[c][2] * t.z;
    }

    float v = wave_reduce64(contrib);
    __shared__ float wsum[4];
    __shared__ int lastflag;
    if ((tid & 63) == 0) wsum[tid >> 6] = v;
    __syncthreads();
    if (tid == 0) {
        atomicAdd(acc, (double)(wsum[0] + wsum[1] + wsum[2] + wsum[3]));
        __threadfence();
        unsigned int old = atomicAdd(counter, 1u);
        lastflag = (old == NBLK - 1) ? 1 : 0;
    }
    __syncthreads();
    if (lastflag) {   // block-uniform condition
        float s = 0.0f;
        if (tid < NPREP) s += pc[tid];
        if (tid + 256 < NPREP) s += pc[tid + 256];
        float v2 = wave_reduce64(s);
        if ((tid & 63) == 0) wsum[tid >> 6] = v2;
        __syncthreads();
        if (tid == 0) {
            double tot = atomicAdd(acc, 0.0);   // device-scope coherent read
            tot += (double)(wsum[0] + wsum[1] + wsum[2] + wsum[3]);
            out[0] = (float)(tot * (1.0 / (double)(Bn * HWn)));
        }
    }
}

extern "C" void kernel_launch(void* const* d_in, const int* in_sizes, int n_in,
                              void* d_out, int out_size, void* d_ws, size_t ws_size,
                              hipStream_t stream)
{
    const float* logit  = (const float*)d_in[0];
    const int*   target = (const int*)d_in[1];
    const float* image  = (const float*)d_in[2];
    const float* srcmap = (const float*)d_in[3];
    const float* dstmap = (const float*)d_in[4];
    float* out = (float*)d_out;

    const size_t NRECG = (size_t)Bn * PP;   // 66,248 padded records
    double*       acc     = (double*)d_ws;
    unsigned int* counter = (unsigned int*)((char*)d_ws + 128);
    float*        pc      = (float*)((char*)d_ws + 256);         // 259 CE partials
    float4*       gA      = (float4*)((char*)d_ws + 4096);
    float2*       gB      = (float2*)((char*)d_ws + 4096 + NRECG * 16);
    float4*       cvec    = (float4*)((char*)d_ws + 4096 + NRECG * 24);

    prep_kernel<<<NPREP, 256, 0, stream>>>(logit, target, image, srcmap, dstmap,
                                           gA, gB, cvec, pc, acc, counter);
    dim3 grid(Wn / TJ, (Hn / TI) * Bn, Kc);
    dim3 blk(TJ, 8);
    gcrf_kernel<<<grid, blk, 0, stream>>>(gA, gB, cvec, pc, acc, counter, out);
}

// Round 14
// 91.432 us; speedup vs baseline: 1.3653x; 1.1181x over previous
//
#include <hip/hip_runtime.h>

#define Bn 2
#define Cn 3
#define Hn 160
#define Wn 160
#define SPANc 11
#define Kc 23
#define HWn (Hn * Wn)
#define PW 182                 // padded dim: 160 + 2*11
#define PP (PW * PW)
#define LAMc 0.15f
#define TJ 32                  // j-tile width (= lanes 0..31)
#define Gc 4                   // centers per thread (vertical)
#define TI 32                  // i-tile height = 8 ty-groups * Gc
#define NROW (TI + Kc - 1)     // 54 staged rows
#define NREC (NROW * TJ)       // 1728 records in LDS (12 B each = 20.7 KB)
#define CEXP (-0.72134752f)    // -0.5 * log2(e)
#define SRGB_S (0.84932190f)   // sqrt(0.5*log2(e)); img pre-scaled so krgb = exp2(-ss)
#define NPREP ((Bn * PP + 255) / 256)   // 259 prep blocks

__device__ __forceinline__ float wave_reduce64(float v) {
#pragma unroll
    for (int off = 32; off > 0; off >>= 1) v += __shfl_down(v, off, 64);
    return v;
}

// pack two floats as bf16 (rne) into one uint: a in high 16, b in low 16
__device__ __forceinline__ unsigned int bf16pk(float a, float b) {
    unsigned int ua = __float_as_uint(a), ub = __float_as_uint(b);
    ua += 0x7fffu + ((ua >> 16) & 1u);
    ub += 0x7fffu + ((ub >> 16) & 1u);
    return (ua & 0xffff0000u) | (ub >> 16);
}

// Fused: zero halo + softmax/pack interior + CE block-partials + zero acc.
// Records (bf16 pairs): gU2=[pk(s*i0,s*i1), pk(s*i2,ys0)], gU1=pk(ys1,ys2); halo=0.
__global__ __launch_bounds__(256) void prep_kernel(
    const float* __restrict__ logit, const int* __restrict__ target,
    const float* __restrict__ image, const float* __restrict__ srcmap,
    const float* __restrict__ dstmap, uint2* __restrict__ gU2,
    unsigned int* __restrict__ gU1, float4* __restrict__ cvec,
    float* __restrict__ pc, double* __restrict__ acc)
{
    int idx = blockIdx.x * 256 + threadIdx.x;
    float ce = 0.0f;
    if (idx < Bn * PP) {
        int b   = idx / PP;
        int rem = idx - b * PP;
        int ip  = rem / PW;
        int jp  = rem - ip * PW;
        int i = ip - SPANc, j = jp - SPANc;
        if ((unsigned)i < (unsigned)Hn && (unsigned)j < (unsigned)Wn) {
            int r = i * Wn + j;
            int p = b * HWn + r;
            const float* lg = logit + (size_t)b * Cn * HWn + r;
            float l0 = lg[0], l1 = lg[HWn], l2 = lg[2 * HWn];
            float m = fmaxf(l0, fmaxf(l1, l2));
            float e0 = __expf(l0 - m), e1 = __expf(l1 - m), e2 = __expf(l2 - m);
            float s = e0 + e1 + e2;
            float inv = 1.0f / s;
            float y0 = e0 * inv, y1 = e1 * inv, y2 = e2 * inv;
            float lse = m + __logf(s);

            const float* im = image + (size_t)b * 3 * HWn + r;
            float i0v = im[0] * SRGB_S, i1v = im[HWn] * SRGB_S, i2v = im[2 * HWn] * SRGB_S;
            float sv = srcmap[p];
            float dv = dstmap[p];

            gU2[idx] = make_uint2(bf16pk(i0v, i1v), bf16pk(i2v, sv * y0));
            gU1[idx] = bf16pk(sv * y1, sv * y2);

            float md = LAMc * (1.0f - dv);
            cvec[p] = make_float4(md * (1.0f - y0), md * (1.0f - y1),
                                  md * (1.0f - y2), 0.0f);

            int t = target[p];
            float lt = (t == 0) ? l0 : ((t == 1) ? l1 : l2);
            ce = (lse - lt) * dv;
        } else {
            gU2[idx] = make_uint2(0u, 0u);
            gU1[idx] = 0u;
        }
    }
    if (idx == 0) *acc = 0.0;   // gcrf launches after this completes

    float v = wave_reduce64(ce);
    __shared__ float wsum[4];
    int tid = threadIdx.x;
    if ((tid & 63) == 0) wsum[tid >> 6] = v;
    __syncthreads();
    if (tid == 0) pc[blockIdx.x] = wsum[0] + wsum[1] + wsum[2] + wsum[3];
}

__device__ __forceinline__ void tap(float p0, float p1, float p2,
                                    float q0, float q1, float q2,
                                    float cA0, float cA1, float cA2,
                                    bool xy_on, float dy2, float dxv,
                                    float& e0, float& e1, float& e2)
{
    float d0 = fmaf(p0, -10.0f, cA0);   // both pre-scaled by SRGB_S
    float d1 = fmaf(p1, -10.0f, cA1);
    float d2 = fmaf(p2, -10.0f, cA2);
    float ss = fmaf(d0, d0, fmaf(d1, d1, d2 * d2));   // = 0.7213 * sum(d_true^2)
    float k = exp2f(-ss);                             // neg folds into v_exp modifier
    if (xy_on) k += exp2f(fmaf(dxv, dxv, dy2) * CEXP);   // exec-masked, rare
    e0 = fmaf(k, q0, e0);
    e1 = fmaf(k, q1, e1);
    e2 = fmaf(k, q2, e2);
}

// Window kernel. Grid: (5, 5*B, 23) = 1150 blocks. Block (32,8). One dj per block.
// Stage 54x32 bf16-packed records (20.7 KB LDS -> occupancy no longer LDS-bound),
// 4 vertically-adjacent centers per thread over 23 di taps. Static 3-phase r-loop
// (R6/R10-proven). Separate finalize dispatch (no per-block device fence: R13
// showed fused-finalize threadfence costs ~10 us).
__global__ __launch_bounds__(256, 4) void gcrf_kernel(
    const uint2* __restrict__ gU2, const unsigned int* __restrict__ gU1,
    const float4* __restrict__ cvec, double* __restrict__ acc)
{
    __shared__ uint2 sU2[NREC];          // pk(i0,i1), pk(i2,ys0)
    __shared__ unsigned int sU1[NREC];   // pk(ys1,ys2)

    int tx = threadIdx.x;                 // 0..31 (j)
    int ty = threadIdx.y;                 // 0..7  (i-group)
    int tid = ty * TJ + tx;
    int jx = blockIdx.x;
    int j  = jx * TJ + tx;
    int by = blockIdx.y;
    int b  = by / 5;
    int it = by - b * 5;
    int i0g = it * TI + ty * Gc;          // first center row of this thread
    int dj = blockIdx.z;                  // 0..22

    size_t g0 = (size_t)b * PP + (size_t)(it * TI) * PW + (jx * TJ + dj);
    for (int n = tid; n < NREC; n += 256) {
        int rr = n >> 5, cc = n & 31;
        size_t gi = g0 + (size_t)rr * PW + cc;
        sU2[n] = gU2[gi];
        sU1[n] = gU1[gi];
    }
    __syncthreads();

    int lbase = ty * Gc * TJ + tx;        // LDS index of (local row ty*Gc, col tx)
    float cA0[Gc], cA1[Gc], cA2[Gc];
#pragma unroll
    for (int c = 0; c < Gc; ++c) {
        uint2 cu = sU2[lbase + (c + SPANc) * TJ];
        cA0[c] = __uint_as_float(cu.x & 0xffff0000u);
        cA1[c] = __uint_as_float(cu.x << 16);
        cA2[c] = __uint_as_float(cu.y & 0xffff0000u);
    }

    // k_xy < 2.3e-29 unless both i<16 and j<16 (source-bug form: d = c - p/6)
    bool xy_on = (j < 16) && (i0g < 16);
    float dy = (float)j - (float)(j + dj - SPANc) * (1.0f / 6.0f);
    float dy2 = dy * dy;
    float fi0 = (float)i0g;

    float eg[Gc][3];
#pragma unroll
    for (int c = 0; c < Gc; ++c) { eg[c][0] = 0.f; eg[c][1] = 0.f; eg[c][2] = 0.f; }

    // prologue r=0..2: center c active iff c <= r
#pragma unroll
    for (int r = 0; r < 3; ++r) {
        uint2 ru = sU2[lbase + r * TJ];
        unsigned int rv = sU1[lbase + r * TJ];
        float p0 = __uint_as_float(ru.x & 0xffff0000u);
        float p1 = __uint_as_float(ru.x << 16);
        float p2 = __uint_as_float(ru.y & 0xffff0000u);
        float q0 = __uint_as_float(ru.y << 16);
        float q1 = __uint_as_float(rv & 0xffff0000u);
        float q2 = __uint_as_float(rv << 16);
        float fpi = fi0 + (float)(r - SPANc);
#pragma unroll
        for (int c = 0; c < 3; ++c) {
            if (c > r) continue;
            tap(p0, p1, p2, q0, q1, q2, cA0[c], cA1[c], cA2[c], xy_on, dy2,
                fi0 + (float)c - fpi * (1.0f / 6.0f), eg[c][0], eg[c][1], eg[c][2]);
        }
    }
    // main r=3..22: all 4 centers active
#pragma unroll 2
    for (int r = 3; r <= 22; ++r) {
        uint2 ru = sU2[lbase + r * TJ];
        unsigned int rv = sU1[lbase + r * TJ];
        float p0 = __uint_as_float(ru.x & 0xffff0000u);
        float p1 = __uint_as_float(ru.x << 16);
        float p2 = __uint_as_float(ru.y & 0xffff0000u);
        float q0 = __uint_as_float(ru.y << 16);
        float q1 = __uint_as_float(rv & 0xffff0000u);
        float q2 = __uint_as_float(rv << 16);
        float fpi = fi0 + (float)(r - SPANc);
#pragma unroll
        for (int c = 0; c < Gc; ++c) {
            tap(p0, p1, p2, q0, q1, q2, cA0[c], cA1[c], cA2[c], xy_on, dy2,
                fi0 + (float)c - fpi * (1.0f / 6.0f), eg[c][0], eg[c][1], eg[c][2]);
        }
    }
    // epilogue r=23..25: center c active iff c >= r-22
#pragma unroll
    for (int r = 23; r <= 25; ++r) {
        uint2 ru = sU2[lbase + r * TJ];
        unsigned int rv = sU1[lbase + r * TJ];
        float p0 = __uint_as_float(ru.x & 0xffff0000u);
        float p1 = __uint_as_float(ru.x << 16);
        float p2 = __uint_as_float(ru.y & 0xffff0000u);
        float q0 = __uint_as_float(ru.y << 16);
        float q1 = __uint_as_float(rv & 0xffff0000u);
        float q2 = __uint_as_float(rv << 16);
        float fpi = fi0 + (float)(r - SPANc);
#pragma unroll
        for (int c = 1; c < Gc; ++c) {
            if (c < r - 22) continue;
            tap(p0, p1, p2, q0, q1, q2, cA0[c], cA1[c], cA2[c], xy_on, dy2,
                fi0 + (float)c - fpi * (1.0f / 6.0f), eg[c][0], eg[c][1], eg[c][2]);
        }
    }

    // epilogue: cvec already holds lam*(1-dst)*(1-y_c)
    const float4* cv = cvec + ((size_t)b * HWn + (size_t)i0g * Wn + j);
    float contrib = 0.0f;
#pragma unroll
    for (int c = 0; c < Gc; ++c) {
        float4 t = cv[(size_t)c * Wn];
        contrib += eg[c][0] * t.x + eg[c][1] * t.y + eg[c][2] * t.z;
    }

    float v = wave_reduce64(contrib);
    __shared__ float wsum[4];
    if ((tid & 63) == 0) wsum[tid >> 6] = v;
    __syncthreads();
    if (tid == 0) atomicAdd(acc, (double)(wsum[0] + wsum[1] + wsum[2] + wsum[3]));
}

// Sum CE block partials + gcrf accumulator -> scalar loss.
__global__ __launch_bounds__(256) void finalize_kernel(
    const float* __restrict__ pc, const double* __restrict__ acc,
    float* __restrict__ out)
{
    int t = threadIdx.x;
    float s = 0.0f;
    if (t < NPREP) s += pc[t];
    if (t + 256 < NPREP) s += pc[t + 256];
    float v = wave_reduce64(s);
    __shared__ float wsum[4];
    if ((t & 63) == 0) wsum[t >> 6] = v;
    __syncthreads();
    if (t == 0) {
        double tot = acc[0] + (double)(wsum[0] + wsum[1] + wsum[2] + wsum[3]);
        out[0] = (float)(tot * (1.0 / (double)(Bn * HWn)));
    }
}

extern "C" void kernel_launch(void* const* d_in, const int* in_sizes, int n_in,
                              void* d_out, int out_size, void* d_ws, size_t ws_size,
                              hipStream_t stream)
{
    const float* logit  = (const float*)d_in[0];
    const int*   target = (const int*)d_in[1];
    const float* image  = (const float*)d_in[2];
    const float* srcmap = (const float*)d_in[3];
    const float* dstmap = (const float*)d_in[4];
    float* out = (float*)d_out;

    const size_t NRECG = (size_t)Bn * PP;   // 66,248 padded records
    double*       acc  = (double*)d_ws;
    float*        pc   = (float*)((char*)d_ws + 256);            // 259 CE partials
    uint2*        gU2  = (uint2*)((char*)d_ws + 4096);
    unsigned int* gU1  = (unsigned int*)((char*)d_ws + 4096 + NRECG * 8);
    float4*       cvec = (float4*)((char*)d_ws + 4096 + NRECG * 12);

    prep_kernel<<<NPREP, 256, 0, stream>>>(logit, target, image, srcmap, dstmap,
                                           gU2, gU1, cvec, pc, acc);
    dim3 grid(Wn / TJ, (Hn / TI) * Bn, Kc);
    dim3 blk(TJ, 8);
    gcrf_kernel<<<grid, blk, 0, stream>>>(gU2, gU1, cvec, acc);
    finalize_kernel<<<1, 256, 0, stream>>>(pc, acc, out);
}

// Round 15
// 85.996 us; speedup vs baseline: 1.4516x; 1.0632x over previous
//
#include <hip/hip_runtime.h>

#define Bn 2
#define Cn 3
#define Hn 160
#define Wn 160
#define SPANc 11
#define Kc 23
#define HWn (Hn * Wn)
#define PW 182                 // padded dim: 160 + 2*11
#define PP (PW * PW)
#define LAMc 0.15f
#define TJ 32                  // j-tile width (= lanes 0..31)
#define Gc 4                   // centers per thread (vertical)
#define TI 32                  // i-tile height = 8 ty-groups * Gc
#define NROW (TI + Kc - 1)     // 54 staged rows
#define NREC (NROW * TJ)       // 1728 records in LDS (12 B each = 20.7 KB)
#define CEXP (-0.72134752f)    // -0.5 * log2(e)
#define SRGB_S (0.84932190f)   // sqrt(0.5*log2(e)); img pre-scaled so krgb = exp2(-ss)
#define NPREP ((Bn * PP + 255) / 256)   // 259 prep blocks

__device__ __forceinline__ float wave_reduce64(float v) {
#pragma unroll
    for (int off = 32; off > 0; off >>= 1) v += __shfl_down(v, off, 64);
    return v;
}

// pack two floats as bf16 (rne) into one uint: a in high 16, b in low 16
__device__ __forceinline__ unsigned int bf16pk(float a, float b) {
    unsigned int ua = __float_as_uint(a), ub = __float_as_uint(b);
    ua += 0x7fffu + ((ua >> 16) & 1u);
    ub += 0x7fffu + ((ub >> 16) & 1u);
    return (ua & 0xffff0000u) | (ub >> 16);
}

// Fused: zero halo + softmax/pack interior + CE block-partials + zero acc.
// Records (bf16 pairs): gU2=[pk(s*i0,s*i1), pk(s*i2,ys0)], gU1=pk(ys1,ys2); halo=0.
__global__ __launch_bounds__(256) void prep_kernel(
    const float* __restrict__ logit, const int* __restrict__ target,
    const float* __restrict__ image, const float* __restrict__ srcmap,
    const float* __restrict__ dstmap, uint2* __restrict__ gU2,
    unsigned int* __restrict__ gU1, float4* __restrict__ cvec,
    float* __restrict__ pc, double* __restrict__ acc)
{
    int idx = blockIdx.x * 256 + threadIdx.x;
    float ce = 0.0f;
    if (idx < Bn * PP) {
        int b   = idx / PP;
        int rem = idx - b * PP;
        int ip  = rem / PW;
        int jp  = rem - ip * PW;
        int i = ip - SPANc, j = jp - SPANc;
        if ((unsigned)i < (unsigned)Hn && (unsigned)j < (unsigned)Wn) {
            int r = i * Wn + j;
            int p = b * HWn + r;
            const float* lg = logit + (size_t)b * Cn * HWn + r;
            float l0 = lg[0], l1 = lg[HWn], l2 = lg[2 * HWn];
            float m = fmaxf(l0, fmaxf(l1, l2));
            float e0 = __expf(l0 - m), e1 = __expf(l1 - m), e2 = __expf(l2 - m);
            float s = e0 + e1 + e2;
            float inv = 1.0f / s;
            float y0 = e0 * inv, y1 = e1 * inv, y2 = e2 * inv;
            float lse = m + __logf(s);

            const float* im = image + (size_t)b * 3 * HWn + r;
            float i0v = im[0] * SRGB_S, i1v = im[HWn] * SRGB_S, i2v = im[2 * HWn] * SRGB_S;
            float sv = srcmap[p];
            float dv = dstmap[p];

            gU2[idx] = make_uint2(bf16pk(i0v, i1v), bf16pk(i2v, sv * y0));
            gU1[idx] = bf16pk(sv * y1, sv * y2);

            float md = LAMc * (1.0f - dv);
            cvec[p] = make_float4(md * (1.0f - y0), md * (1.0f - y1),
                                  md * (1.0f - y2), 0.0f);

            int t = target[p];
            float lt = (t == 0) ? l0 : ((t == 1) ? l1 : l2);
            ce = (lse - lt) * dv;
        } else {
            gU2[idx] = make_uint2(0u, 0u);
            gU1[idx] = 0u;
        }
    }
    if (idx == 0) *acc = 0.0;   // gcrf launches after this completes

    float v = wave_reduce64(ce);
    __shared__ float wsum[4];
    int tid = threadIdx.x;
    if ((tid & 63) == 0) wsum[tid >> 6] = v;
    __syncthreads();
    if (tid == 0) pc[blockIdx.x] = wsum[0] + wsum[1] + wsum[2] + wsum[3];
}

// One tap. XY=false: pure 10-op rgb kernel (3 diff fma, 3 ss, 1 exp2, 3 acc fma).
template<bool XY>
__device__ __forceinline__ void tap(float p0, float p1, float p2,
                                    float q0, float q1, float q2,
                                    float cA0, float cA1, float cA2,
                                    bool xy_on, float dy2, float dxv,
                                    float& e0, float& e1, float& e2)
{
    float d0 = fmaf(p0, -10.0f, cA0);   // both pre-scaled by SRGB_S
    float d1 = fmaf(p1, -10.0f, cA1);
    float d2 = fmaf(p2, -10.0f, cA2);
    float ss = fmaf(d0, d0, fmaf(d1, d1, d2 * d2));   // = 0.7213 * sum(d_true^2)
    float k = exp2f(-ss);                             // neg folds into v_exp modifier
    if constexpr (XY) {
        if (xy_on) k += exp2f(fmaf(dxv, dxv, dy2) * CEXP);   // 46/1150 blocks only
    }
    e0 = fmaf(k, q0, e0);
    e1 = fmaf(k, q1, e1);
    e2 = fmaf(k, q2, e2);
}

// 3-phase window loop over staged LDS records (R6/R10/R14-proven shape).
template<bool XY>
__device__ __forceinline__ void window_loop(
    const uint2* sU2, const unsigned int* sU1, int lbase,
    const float* cA0, const float* cA1, const float* cA2,
    bool xy_on, float dy2, float fi0, float eg[Gc][3])
{
    // prologue r=0..2: center c active iff c <= r
#pragma unroll
    for (int r = 0; r < 3; ++r) {
        uint2 ru = sU2[lbase + r * TJ];
        unsigned int rv = sU1[lbase + r * TJ];
        float p0 = __uint_as_float(ru.x & 0xffff0000u);
        float p1 = __uint_as_float(ru.x << 16);
        float p2 = __uint_as_float(ru.y & 0xffff0000u);
        float q0 = __uint_as_float(ru.y << 16);
        float q1 = __uint_as_float(rv & 0xffff0000u);
        float q2 = __uint_as_float(rv << 16);
        float dxb = XY ? (fi0 - (fi0 + (float)(r - SPANc)) * (1.0f / 6.0f)) : 0.0f;
#pragma unroll
        for (int c = 0; c < 3; ++c) {
            if (c > r) continue;
            tap<XY>(p0, p1, p2, q0, q1, q2, cA0[c], cA1[c], cA2[c], xy_on, dy2,
                    dxb + (float)c, eg[c][0], eg[c][1], eg[c][2]);
        }
    }
    // main r=3..22: all 4 centers active
#pragma unroll 2
    for (int r = 3; r <= 22; ++r) {
        uint2 ru = sU2[lbase + r * TJ];
        unsigned int rv = sU1[lbase + r * TJ];
        float p0 = __uint_as_float(ru.x & 0xffff0000u);
        float p1 = __uint_as_float(ru.x << 16);
        float p2 = __uint_as_float(ru.y & 0xffff0000u);
        float q0 = __uint_as_float(ru.y << 16);
        float q1 = __uint_as_float(rv & 0xffff0000u);
        float q2 = __uint_as_float(rv << 16);
        float dxb = XY ? (fi0 - (fi0 + (float)(r - SPANc)) * (1.0f / 6.0f)) : 0.0f;
#pragma unroll
        for (int c = 0; c < Gc; ++c) {
            tap<XY>(p0, p1, p2, q0, q1, q2, cA0[c], cA1[c], cA2[c], xy_on, dy2,
                    dxb + (float)c, eg[c][0], eg[c][1], eg[c][2]);
        }
    }
    // epilogue r=23..25: center c active iff c >= r-22
#pragma unroll
    for (int r = 23; r <= 25; ++r) {
        uint2 ru = sU2[lbase + r * TJ];
        unsigned int rv = sU1[lbase + r * TJ];
        float p0 = __uint_as_float(ru.x & 0xffff0000u);
        float p1 = __uint_as_float(ru.x << 16);
        float p2 = __uint_as_float(ru.y & 0xffff0000u);
        float q0 = __uint_as_float(ru.y << 16);
        float q1 = __uint_as_float(rv & 0xffff0000u);
        float q2 = __uint_as_float(rv << 16);
        float dxb = XY ? (fi0 - (fi0 + (float)(r - SPANc)) * (1.0f / 6.0f)) : 0.0f;
#pragma unroll
        for (int c = 1; c < Gc; ++c) {
            if (c < r - 22) continue;
            tap<XY>(p0, p1, p2, q0, q1, q2, cA0[c], cA1[c], cA2[c], xy_on, dy2,
                    dxb + (float)c, eg[c][0], eg[c][1], eg[c][2]);
        }
    }
}

// Window kernel. Grid: (5, 5*B, 23) = 1150 blocks. Block (32,8). One dj per block.
// Stage 54x32 bf16-packed records (20.7 KB LDS), 4 vertically-adjacent centers per
// thread over 23 di taps. Block-uniform fast/slow split: only jx==0 && it==0 blocks
// (46 of 1150) can have any lane with k_xy > 2.3e-29; all others run the 10-op tap.
__global__ __launch_bounds__(256, 4) void gcrf_kernel(
    const uint2* __restrict__ gU2, const unsigned int* __restrict__ gU1,
    const float4* __restrict__ cvec, double* __restrict__ acc)
{
    __shared__ uint2 sU2[NREC];          // pk(i0,i1), pk(i2,ys0)
    __shared__ unsigned int sU1[NREC];   // pk(ys1,ys2)

    int tx = threadIdx.x;                 // 0..31 (j)
    int ty = threadIdx.y;                 // 0..7  (i-group)
    int tid = ty * TJ + tx;
    int jx = blockIdx.x;
    int j  = jx * TJ + tx;
    int by = blockIdx.y;
    int b  = by / 5;
    int it = by - b * 5;
    int i0g = it * TI + ty * Gc;          // first center row of this thread
    int dj = blockIdx.z;                  // 0..22

    size_t g0 = (size_t)b * PP + (size_t)(it * TI) * PW + (jx * TJ + dj);
    for (int n = tid; n < NREC; n += 256) {
        int rr = n >> 5, cc = n & 31;
        size_t gi = g0 + (size_t)rr * PW + cc;
        sU2[n] = gU2[gi];
        sU1[n] = gU1[gi];
    }
    __syncthreads();

    int lbase = ty * Gc * TJ + tx;        // LDS index of (local row ty*Gc, col tx)
    float cA0[Gc], cA1[Gc], cA2[Gc];
#pragma unroll
    for (int c = 0; c < Gc; ++c) {
        uint2 cu = sU2[lbase + (c + SPANc) * TJ];
        cA0[c] = __uint_as_float(cu.x & 0xffff0000u);
        cA1[c] = __uint_as_float(cu.x << 16);
        cA2[c] = __uint_as_float(cu.y & 0xffff0000u);
    }

    // k_xy < 2.3e-29 unless both i<16 and j<16 (source-bug form: d = c - p/6)
    bool xy_on = (j < 16) && (i0g < 16);
    float dy = (float)j - (float)(j + dj - SPANc) * (1.0f / 6.0f);
    float dy2 = dy * dy;
    float fi0 = (float)i0g;

    float eg[Gc][3];
#pragma unroll
    for (int c = 0; c < Gc; ++c) { eg[c][0] = 0.f; eg[c][1] = 0.f; eg[c][2] = 0.f; }

    if (jx == 0 && it == 0) {   // block-uniform: the only blocks where xy_on can hold
        window_loop<true>(sU2, sU1, lbase, cA0, cA1, cA2, xy_on, dy2, fi0, eg);
    } else {
        window_loop<false>(sU2, sU1, lbase, cA0, cA1, cA2, false, dy2, fi0, eg);
    }

    // epilogue: cvec already holds lam*(1-dst)*(1-y_c)
    const float4* cv = cvec + ((size_t)b * HWn + (size_t)i0g * Wn + j);
    float contrib = 0.0f;
#pragma unroll
    for (int c = 0; c < Gc; ++c) {
        float4 t = cv[(size_t)c * Wn];
        contrib += eg[c][0] * t.x + eg[c][1] * t.y + eg[c][2] * t.z;
    }

    float v = wave_reduce64(contrib);
    __shared__ float wsum[4];
    if ((tid & 63) == 0) wsum[tid >> 6] = v;
    __syncthreads();
    if (tid == 0) atomicAdd(acc, (double)(wsum[0] + wsum[1] + wsum[2] + wsum[3]));
}

// Sum CE block partials + gcrf accumulator -> scalar loss.
__global__ __launch_bounds__(256) void finalize_kernel(
    const float* __restrict__ pc, const double* __restrict__ acc,
    float* __restrict__ out)
{
    int t = threadIdx.x;
    float s = 0.0f;
    if (t < NPREP) s += pc[t];
    if (t + 256 < NPREP) s += pc[t + 256];
    float v = wave_reduce64(s);
    __shared__ float wsum[4];
    if ((t & 63) == 0) wsum[t >> 6] = v;
    __syncthreads();
    if (t == 0) {
        double tot = acc[0] + (double)(wsum[0] + wsum[1] + wsum[2] + wsum[3]);
        out[0] = (float)(tot * (1.0 / (double)(Bn * HWn)));
    }
}

extern "C" void kernel_launch(void* const* d_in, const int* in_sizes, int n_in,
                              void* d_out, int out_size, void* d_ws, size_t ws_size,
                              hipStream_t stream)
{
    const float* logit  = (const float*)d_in[0];
    const int*   target = (const int*)d_in[1];
    const float* image  = (const float*)d_in[2];
    const float* srcmap = (const float*)d_in[3];
    const float* dstmap = (const float*)d_in[4];
    float* out = (float*)d_out;

    const size_t NRECG = (size_t)Bn * PP;   // 66,248 padded records
    double*       acc  = (double*)d_ws;
    float*        pc   = (float*)((char*)d_ws + 256);            // 259 CE partials
    uint2*        gU2  = (uint2*)((char*)d_ws + 4096);
    unsigned int* gU1  = (unsigned int*)((char*)d_ws + 4096 + NRECG * 8);
    float4*       cvec = (float4*)((char*)d_ws + 4096 + NRECG * 12);

    prep_kernel<<<NPREP, 256, 0, stream>>>(logit, target, image, srcmap, dstmap,
                                           gU2, gU1, cvec, pc, acc);
    dim3 grid(Wn / TJ, (Hn / TI) * Bn, Kc);
    dim3 blk(TJ, 8);
    gcrf_kernel<<<grid, blk, 0, stream>>>(gU2, gU1, cvec, acc);
    finalize_kernel<<<1, 256, 0, stream>>>(pc, acc, out);
}

// Round 17
// 85.230 us; speedup vs baseline: 1.4647x; 1.0090x over previous
//
#include <hip/hip_runtime.h>

#define Bn 2
#define Cn 3
#define Hn 160
#define Wn 160
#define SPANc 11
#define Kc 23
#define HWn (Hn * Wn)
#define PW 182                 // padded dim: 160 + 2*11
#define PP (PW * PW)
#define LAMc 0.15f
#define INVN (1.0f / (float)(Bn * HWn))
#define TJ 32                  // j-tile width (= lanes 0..31)
#define Gc 4                   // centers per thread (vertical)
#define TI 32                  // i-tile height = 8 ty-groups * Gc
#define NROW (TI + Kc - 1)     // 54 staged rows
#define NREC (NROW * TJ)       // 1728 records in LDS (16 B each = 27.6 KB)
#define CEXP (-0.72134752f)    // -0.5 * log2(e)
#define CX   (14.42695041f)    // 20 * 0.72134752  (cross-term scale)
#define CA   (0.72134752f)
#define NPREP ((Bn * PP + 255) / 256)   // 259 prep blocks

__device__ __forceinline__ float wave_reduce64(float v) {
#pragma unroll
    for (int off = 32; off > 0; off >>= 1) v += __shfl_down(v, off, 64);
    return v;
}

// pack two floats as bf16 (rne) into one uint: a in high 16, b in low 16
__device__ __forceinline__ unsigned int bf16pk(float a, float b) {
    unsigned int ua = __float_as_uint(a), ub = __float_as_uint(b);
    ua += 0x7fffu + ((ua >> 16) & 1u);
    ub += 0x7fffu + ((ub >> 16) & 1u);
    return (ua & 0xffff0000u) | (ub >> 16);
}

// Fused: zero halo + softmax/pack interior + CE block-partials (pre-scaled) + zero out.
// Record uint4: [pk(p0,p1), pk(p2,mB), pk(q0,q1), pk(q2,0)]
//   p = raw image, mB = -72.13*sum(p^2) (fp32-computed, bf16-stored), q = src*y.
// exp2 exponent identity: -0.7213*sum((c-10p)^2) = (14.427*sum(c*p)) - A - B.
__global__ __launch_bounds__(256) void prep_kernel(
    const float* __restrict__ logit, const int* __restrict__ target,
    const float* __restrict__ image, const float* __restrict__ srcmap,
    const float* __restrict__ dstmap, uint4* __restrict__ gU4,
    float4* __restrict__ cvec, float* __restrict__ pc, float* __restrict__ out)
{
    int idx = blockIdx.x * 256 + threadIdx.x;
    float ce = 0.0f;
    if (idx < Bn * PP) {
        int b   = idx / PP;
        int rem = idx - b * PP;
        int ip  = rem / PW;
        int jp  = rem - ip * PW;
        int i = ip - SPANc, j = jp - SPANc;
        if ((unsigned)i < (unsigned)Hn && (unsigned)j < (unsigned)Wn) {
            int r = i * Wn + j;
            int p = b * HWn + r;
            const float* lg = logit + (size_t)b * Cn * HWn + r;
            float l0 = lg[0], l1 = lg[HWn], l2 = lg[2 * HWn];
            float m = fmaxf(l0, fmaxf(l1, l2));
            float e0 = __expf(l0 - m), e1 = __expf(l1 - m), e2 = __expf(l2 - m);
            float s = e0 + e1 + e2;
            float inv = 1.0f / s;
            float y0 = e0 * inv, y1 = e1 * inv, y2 = e2 * inv;
            float lse = m + __logf(s);

            const float* im = image + (size_t)b * 3 * HWn + r;
            float p0 = im[0], p1 = im[HWn], p2 = im[2 * HWn];
            float sv = srcmap[p];
            float dv = dstmap[p];

            float B = (p0 * p0 + p1 * p1 + p2 * p2) * (100.0f * CA);
            gU4[idx] = make_uint4(bf16pk(p0, p1), bf16pk(p2, -B),
                                  bf16pk(sv * y0, sv * y1), bf16pk(sv * y2, 0.0f));

            float md = LAMc * (1.0f - dv) * INVN;
            cvec[p] = make_float4(md * (1.0f - y0), md * (1.0f - y1),
                                  md * (1.0f - y2), 0.0f);

            int t = target[p];
            float lt = (t == 0) ? l0 : ((t == 1) ? l1 : l2);
            ce = (lse - lt) * dv * INVN;
        } else {
            gU4[idx] = make_uint4(0u, 0u, 0u, 0u);
        }
    }
    if (idx == 0) out[0] = 0.0f;   // gcrf launches after this completes (stream order)

    float v = wave_reduce64(ce);
    __shared__ float wsum[4];
    int tid = threadIdx.x;
    if ((tid & 63) == 0) wsum[tid >> 6] = v;
    __syncthreads();
    if (tid == 0) pc[blockIdx.x] = wsum[0] + wsum[1] + wsum[2] + wsum[3];
}

// One tap: e = c.p chain seeded with mB; k = exp2(e + mA); acc. 8 VALU ops.
template<bool XY>
__device__ __forceinline__ void tap(float p0, float p1, float p2, float mB,
                                    float q0, float q1, float q2,
                                    float c0s, float c1s, float c2s, float mA,
                                    bool xy_on, float dy2, float dxv,
                                    float& e0, float& e1, float& e2)
{
    float e = fmaf(c0s, p0, fmaf(c1s, p1, fmaf(c2s, p2, mB)));
    float k = exp2f(e + mA);
    if constexpr (XY) {
        if (xy_on) k += exp2f(fmaf(dxv, dxv, dy2) * CEXP);   // 46/1150 blocks only
    }
    e0 = fmaf(k, q0, e0);
    e1 = fmaf(k, q1, e1);
    e2 = fmaf(k, q2, e2);
}

// 3-phase window loop over staged LDS records (R6/R10/R14/R15-proven shape).
template<bool XY>
__device__ __forceinline__ void window_loop(
    const uint4* sU4, int lbase,
    const float* c0s, const float* c1s, const float* c2s, const float* mA,
    bool xy_on, float dy2, float fi0, float eg[Gc][3])
{
#pragma unroll
    for (int r = 0; r < 3; ++r) {
        uint4 ru = sU4[lbase + r * TJ];
        float p0 = __uint_as_float(ru.x & 0xffff0000u);
        float p1 = __uint_as_float(ru.x << 16);
        float p2 = __uint_as_float(ru.y & 0xffff0000u);
        float mB = __uint_as_float(ru.y << 16);
        float q0 = __uint_as_float(ru.z & 0xffff0000u);
        float q1 = __uint_as_float(ru.z << 16);
        float q2 = __uint_as_float(ru.w & 0xffff0000u);
        float dxb = XY ? (fi0 - (fi0 + (float)(r - SPANc)) * (1.0f / 6.0f)) : 0.0f;
#pragma unroll
        for (int c = 0; c < 3; ++c) {
            if (c > r) continue;
            tap<XY>(p0, p1, p2, mB, q0, q1, q2, c0s[c], c1s[c], c2s[c], mA[c],
                    xy_on, dy2, dxb + (float)c, eg[c][0], eg[c][1], eg[c][2]);
        }
    }
#pragma unroll 2
    for (int r = 3; r <= 22; ++r) {
        uint4 ru = sU4[lbase + r * TJ];
        float p0 = __uint_as_float(ru.x & 0xffff0000u);
        float p1 = __uint_as_float(ru.x << 16);
        float p2 = __uint_as_float(ru.y & 0xffff0000u);
        float mB = __uint_as_float(ru.y << 16);
        float q0 = __uint_as_float(ru.z & 0xffff0000u);
        float q1 = __uint_as_float(ru.z << 16);
        float q2 = __uint_as_float(ru.w & 0xffff0000u);
        float dxb = XY ? (fi0 - (fi0 + (float)(r - SPANc)) * (1.0f / 6.0f)) : 0.0f;
#pragma unroll
        for (int c = 0; c < Gc; ++c) {
            tap<XY>(p0, p1, p2, mB, q0, q1, q2, c0s[c], c1s[c], c2s[c], mA[c],
                    xy_on, dy2, dxb + (float)c, eg[c][0], eg[c][1], eg[c][2]);
        }
    }
#pragma unroll
    for (int r = 23; r <= 25; ++r) {
        uint4 ru = sU4[lbase + r * TJ];
        float p0 = __uint_as_float(ru.x & 0xffff0000u);
        float p1 = __uint_as_float(ru.x << 16);
        float p2 = __uint_as_float(ru.y & 0xffff0000u);
        float mB = __uint_as_float(ru.y << 16);
        float q0 = __uint_as_float(ru.z & 0xffff0000u);
        float q1 = __uint_as_float(ru.z << 16);
        float q2 = __uint_as_float(ru.w & 0xffff0000u);
        float dxb = XY ? (fi0 - (fi0 + (float)(r - SPANc)) * (1.0f / 6.0f)) : 0.0f;
#pragma unroll
        for (int c = 1; c < Gc; ++c) {
            if (c < r - 22) continue;
            tap<XY>(p0, p1, p2, mB, q0, q1, q2, c0s[c], c1s[c], c2s[c], mA[c],
                    xy_on, dy2, dxb + (float)c, eg[c][0], eg[c][1], eg[c][2]);
        }
    }
}

// Window kernel. Grid: (5, 5*B, 23) = 1150 blocks. Block (32,8). One dj per block.
// Stage 54x32 uint4 records (27.6 KB LDS, single ds_read_b128 per record).
// Each block float-atomicAdds its pre-scaled contribution into out[0] (no finalize
// dispatch, no device fence — R13 lesson). One designated non-XY block also reduces
// the 259 CE partials.
__global__ __launch_bounds__(256, 4) void gcrf_kernel(
    const uint4* __restrict__ gU4, const float4* __restrict__ cvec,
    const float* __restrict__ pc, float* __restrict__ out)
{
    __shared__ uint4 sU4[NREC];

    int tx = threadIdx.x;                 // 0..31 (j)
    int ty = threadIdx.y;                 // 0..7  (i-group)
    int tid = ty * TJ + tx;
    int jx = blockIdx.x;
    int j  = jx * TJ + tx;
    int by = blockIdx.y;
    int b  = by / 5;
    int it = by - b * 5;
    int i0g = it * TI + ty * Gc;          // first center row of this thread
    int dj = blockIdx.z;                  // 0..22

    size_t g0 = (size_t)b * PP + (size_t)(it * TI) * PW + (jx * TJ + dj);
    for (int n = tid; n < NREC; n += 256) {
        int rr = n >> 5, cc = n & 31;
        sU4[n] = gU4[g0 + (size_t)rr * PW + cc];
    }
    __syncthreads();

    int lbase = ty * Gc * TJ + tx;        // LDS index of (local row ty*Gc, col tx)
    float c0s[Gc], c1s[Gc], c2s[Gc], mA[Gc];
#pragma unroll
    for (int c = 0; c < Gc; ++c) {
        uint4 cu = sU4[lbase + (c + SPANc) * TJ];
        float cc0 = __uint_as_float(cu.x & 0xffff0000u);
        float cc1 = __uint_as_float(cu.x << 16);
        float cc2 = __uint_as_float(cu.y & 0xffff0000u);
        c0s[c] = cc0 * CX; c1s[c] = cc1 * CX; c2s[c] = cc2 * CX;
        mA[c] = -CA * fmaf(cc0, cc0, fmaf(cc1, cc1, cc2 * cc2));
    }

    // k_xy < 2.3e-29 unless both i<16 and j<16 (source-bug form: d = c - p/6)
    bool xy_on = (j < 16) && (i0g < 16);
    float dy = (float)j - (float)(j + dj - SPANc) * (1.0f / 6.0f);
    float dy2 = dy * dy;
    float fi0 = (float)i0g;

    float eg[Gc][3];
#pragma unroll
    for (int c = 0; c < Gc; ++c) { eg[c][0] = 0.f; eg[c][1] = 0.f; eg[c][2] = 0.f; }

    if (jx == 0 && it == 0) {   // block-uniform: only blocks where xy_on can hold
        window_loop<true>(sU4, lbase, c0s, c1s, c2s, mA, xy_on, dy2, fi0, eg);
    } else {
        window_loop<false>(sU4, lbase, c0s, c1s, c2s, mA, false, dy2, fi0, eg);
    }

    // epilogue: cvec already holds lam*(1-dst)*(1-y_c)/(B*HW)
    const float4* cv = cvec + ((size_t)b * HWn + (size_t)i0g * Wn + j);
    float contrib = 0.0f;
#pragma unroll
    for (int c = 0; c < Gc; ++c) {
        float4 t = cv[(size_t)c * Wn];
        contrib += eg[c][0] * t.x + eg[c][1] * t.y + eg[c][2] * t.z;
    }

    float v = wave_reduce64(contrib);
    __shared__ float wsum[4];
    if ((tid & 63) == 0) wsum[tid >> 6] = v;
    __syncthreads();
    if (tid == 0) atomicAdd(out, wsum[0] + wsum[1] + wsum[2] + wsum[3]);

    // designated non-XY block folds in the (pre-scaled) CE partial sums
    if (jx == 4 && by == 9 && dj == 22) {
        float s = 0.0f;
        if (tid < NPREP) s += pc[tid];
        if (tid + 256 < NPREP) s += pc[tid + 256];
        float v2 = wave_reduce64(s);
        __syncthreads();
        if ((tid & 63) == 0) wsum[tid >> 6] = v2;
        __syncthreads();
        if (tid == 0) atomicAdd(out, wsum[0] + wsum[1] + wsum[2] + wsum[3]);
    }
}

extern "C" void kernel_launch(void* const* d_in, const int* in_sizes, int n_in,
                              void* d_out, int out_size, void* d_ws, size_t ws_size,
                              hipStream_t stream)
{
    const float* logit  = (const float*)d_in[0];
    const int*   target = (const int*)d_in[1];
    const float* image  = (const float*)d_in[2];
    const float* srcmap = (const float*)d_in[3];
    const float* dstmap = (const float*)d_in[4];
    float* out = (float*)d_out;

    const size_t NRECG = (size_t)Bn * PP;   // 66,248 padded records
    float*  pc   = (float*)((char*)d_ws + 256);                  // 259 CE partials
    uint4*  gU4  = (uint4*)((char*)d_ws + 4096);
    float4* cvec = (float4*)((char*)d_ws + 4096 + NRECG * 16);

    prep_kernel<<<NPREP, 256, 0, stream>>>(logit, target, image, srcmap, dstmap,
                                           gU4, cvec, pc, out);
    dim3 grid(Wn / TJ, (Hn / TI) * Bn, Kc);
    dim3 blk(TJ, 8);
    gcrf_kernel<<<grid, blk, 0, stream>>>(gU4, cvec, pc, out);
}